// Round 4
// baseline (432.150 us; speedup 1.0000x reference)
//
#include <hip/hip_runtime.h>

#define IN_F 128
#define OUT_F 128
#define KER 4

typedef unsigned int uint;
typedef unsigned short u16;
typedef __attribute__((ext_vector_type(8))) short bf16x8;
typedef __attribute__((ext_vector_type(4))) float f32x4;

__device__ __forceinline__ uint f2bf(float f) {
    uint u = __float_as_uint(f);
    u += 0x7fffu + ((u >> 16) & 1u);
    return u >> 16;
}

// ---- fused prep: x->bf16 + dom extract | W repack to frag layout | zero counts + kernel consts ----

__global__ void __launch_bounds__(256) prep_kernel(
    const float* __restrict__ x, const float* __restrict__ weight,
    const float* __restrict__ mu, const float* __restrict__ sig, int n,
    u16* __restrict__ xbf, float4* __restrict__ dom, u16* __restrict__ W2p,
    int* __restrict__ counts, float* __restrict__ kc, int nB1, int nB2) {
    const int b = blockIdx.x;
    if (b < nB1) {
        int t = b * 256 + threadIdx.x;               // one thread = 4 floats
        if (t < n * 32) {
            float4 v = *reinterpret_cast<const float4*>(x + (size_t)t * 4);
            uint2 o;
            o.x = f2bf(v.x) | (f2bf(v.y) << 16);
            o.y = f2bf(v.z) | (f2bf(v.w) << 16);
            *reinterpret_cast<uint2*>(xbf + (size_t)t * 4) = o;
            if ((t & 31) == 0) dom[t >> 5] = make_float4(v.x, v.y, v.z, 0.f);
        }
    } else if (b < nB1 + nB2) {
        int t = (b - nB1) * 256 + threadIdx.x;       // 0..8191, one B-fragment-lane each
        if (t < 8192) {
            int lane = t & 63;
            int nfks = t >> 6;                        // (nf*16 + ks)
            int ks = nfks & 15, nf = nfks >> 4;
            int f = nf * 16 + (lane & 15);
            int kbase = ks * 32 + ((lane >> 4) << 3);
            uint pk[4];
            #pragma unroll
            for (int jj = 0; jj < 4; ++jj) {
                int k0 = kbase + jj * 2;
                int c0 = k0 & 127, q0 = k0 >> 7;
                int k1 = k0 + 1;
                int c1 = k1 & 127, q1 = k1 >> 7;
                uint lo = f2bf(weight[((size_t)c0 * OUT_F + f) * KER + q0]);
                uint hi = f2bf(weight[((size_t)c1 * OUT_F + f) * KER + q1]);
                pk[jj] = lo | (hi << 16);
            }
            *reinterpret_cast<uint4*>(W2p + (size_t)t * 8) =
                make_uint4(pk[0], pk[1], pk[2], pk[3]);
        }
    } else {
        int t = (b - nB1 - nB2) * 256 + threadIdx.x;
        if (t < n) counts[t] = 0;
        if (b == nB1 + nB2 && threadIdx.x < KER) {
            // v_k = exp(A_k + B_k*S + C0_k*d0 + C1_k*d1 + C2_k*d2), S = |d|^2
            int k = threadIdx.x;
            float sg = sig[k];
            float m0 = mu[k], m1 = mu[KER + k], m2 = mu[2 * KER + k];
            kc[k * 5 + 0] = -0.5f * sg * (m0 * m0 + m1 * m1 + m2 * m2);
            kc[k * 5 + 1] = -0.5f * sg;
            kc[k * 5 + 2] = sg * m0;
            kc[k * 5 + 3] = sg * m1;
            kc[k * 5 + 4] = sg * m2;
        }
    }
}

// ---------------- CSR build ----------------

__global__ void hist_kernel(const int* __restrict__ row, int E, int* __restrict__ counts) {
    int e = blockIdx.x * blockDim.x + threadIdx.x;
    if (e < E) atomicAdd(&counts[row[e]], 1);
}

__global__ void scanA_kernel(const int* __restrict__ counts, int n, int* __restrict__ bsum) {
    __shared__ int wsum[16];
    int i = blockIdx.x * 1024 + threadIdx.x;
    int lane = threadIdx.x & 63, wv = threadIdx.x >> 6;
    int v = (i < n) ? counts[i] : 0;
    #pragma unroll
    for (int off = 32; off > 0; off >>= 1) v += __shfl_down(v, off, 64);
    if (lane == 0) wsum[wv] = v;
    __syncthreads();
    if (threadIdx.x == 0) {
        int t = 0;
        #pragma unroll
        for (int q = 0; q < 16; ++q) t += wsum[q];
        bsum[blockIdx.x] = t;
    }
}

// scanC with folded block-offset reduction (requires gridDim <= 64, i.e. n <= 65536)
__global__ void scanC_kernel(const int* __restrict__ counts, int n, const int* __restrict__ bsum,
                             int* __restrict__ row_ptr, int* __restrict__ cursor) {
    __shared__ int wsum[16];
    __shared__ int s_boff;
    const int tid = threadIdx.x, lane = tid & 63, wv = tid >> 6;
    const int i = blockIdx.x * 1024 + tid;
    if (tid < 64) {
        int v = (tid < blockIdx.x) ? bsum[tid] : 0;
        #pragma unroll
        for (int off = 32; off > 0; off >>= 1) v += __shfl_down(v, off, 64);
        if (tid == 0) s_boff = v;
    }
    int v = (i < n) ? counts[i] : 0;
    int s = v;
    #pragma unroll
    for (int off = 1; off < 64; off <<= 1) {
        int t = __shfl_up(s, off, 64);
        if (lane >= off) s += t;
    }
    if (lane == 63) wsum[wv] = s;
    __syncthreads();
    if (wv == 0 && lane < 16) {
        int w = wsum[lane];
        #pragma unroll
        for (int off = 1; off < 16; off <<= 1) {
            int t = __shfl_up(w, off, 64);
            if (lane >= off) w += t;
        }
        wsum[lane] = w;
    }
    __syncthreads();
    int base = s_boff + (wv ? wsum[wv - 1] : 0);
    int incl = base + s;
    if (i < n) { row_ptr[i + 1] = incl; cursor[i] = incl - v; }
    if (i == 0) row_ptr[0] = 0;
}

// Scatter: sort only the 4B col index into CSR order (6.4MB working set -> L2-mergeable)
__global__ void scatter_kernel(const int* __restrict__ row, const int* __restrict__ col, int E,
                               int* __restrict__ cursor, int* __restrict__ col_sorted) {
    int e = blockIdx.x * blockDim.x + threadIdx.x;
    if (e >= E) return;
    int r = row[e];
    int pos = atomicAdd(&cursor[r], 1);
    col_sorted[pos] = col[e];
}

// ---- Aggregation: one wave per row; recompute gaussian values from dom; 4-edge MLP ----

__global__ void __launch_bounds__(64) agg_kernel(
    const u16* __restrict__ xbf, const int* __restrict__ row_ptr,
    const int* __restrict__ col_sorted, const float4* __restrict__ dom,
    const float* __restrict__ kc, u16* __restrict__ aggbf, int n) {
    const int i = blockIdx.x;
    const int l = threadIdx.x;
    const int start = row_ptr[i];
    const int end   = row_ptr[i + 1];
    const float4 dr = dom[i];
    float A[4], B[4], C0[4], C1[4], C2[4];
    #pragma unroll
    for (int k = 0; k < 4; ++k) {
        A[k]  = kc[k * 5 + 0];
        B[k]  = kc[k * 5 + 1];
        C0[k] = kc[k * 5 + 2];
        C1[k] = kc[k * 5 + 3];
        C2[k] = kc[k * 5 + 4];
    }

    float acc[4][2];
    #pragma unroll
    for (int k = 0; k < 4; ++k) { acc[k][0] = 0.f; acc[k][1] = 0.f; }

    auto body = [&](float qx, float qy, float qz, uint xp) {
        float d0 = dr.x - qx, d1 = dr.y - qy, d2 = dr.z - qz;
        float S = fmaf(d2, d2, fmaf(d1, d1, d0 * d0));
        float x0 = __uint_as_float(xp << 16);
        float x1 = __uint_as_float(xp & 0xffff0000u);
        #pragma unroll
        for (int k = 0; k < 4; ++k) {
            float t = fmaf(B[k], S, A[k]);
            t = fmaf(C0[k], d0, t);
            t = fmaf(C1[k], d1, t);
            t = fmaf(C2[k], d2, t);
            float v = __expf(t);
            acc[k][0] = fmaf(v, x0, acc[k][0]);
            acc[k][1] = fmaf(v, x1, acc[k][1]);
        }
    };

    int j = start;
    for (; j + 4 <= end; j += 4) {
        int c0 = col_sorted[j + 0];
        int c1 = col_sorted[j + 1];
        int c2 = col_sorted[j + 2];
        int c3 = col_sorted[j + 3];
        float4 q0 = dom[c0];
        float4 q1 = dom[c1];
        float4 q2 = dom[c2];
        float4 q3 = dom[c3];
        uint xp0 = *reinterpret_cast<const uint*>(xbf + ((size_t)c0 << 7) + (l << 1));
        uint xp1 = *reinterpret_cast<const uint*>(xbf + ((size_t)c1 << 7) + (l << 1));
        uint xp2 = *reinterpret_cast<const uint*>(xbf + ((size_t)c2 << 7) + (l << 1));
        uint xp3 = *reinterpret_cast<const uint*>(xbf + ((size_t)c3 << 7) + (l << 1));
        body(q0.x, q0.y, q0.z, xp0);
        body(q1.x, q1.y, q1.z, xp1);
        body(q2.x, q2.y, q2.z, xp2);
        body(q3.x, q3.y, q3.z, xp3);
    }
    for (; j < end; ++j) {
        int c = col_sorted[j];
        float4 q = dom[c];
        uint xp = *reinterpret_cast<const uint*>(xbf + ((size_t)c << 7) + (l << 1));
        body(q.x, q.y, q.z, xp);
    }

    u16* o = aggbf + ((size_t)i << 9) + (l << 1);
    *reinterpret_cast<uint*>(o +   0) = f2bf(acc[0][0]) | (f2bf(acc[0][1]) << 16);
    *reinterpret_cast<uint*>(o + 128) = f2bf(acc[1][0]) | (f2bf(acc[1][1]) << 16);
    *reinterpret_cast<uint*>(o + 256) = f2bf(acc[2][0]) | (f2bf(acc[2][1]) << 16);
    *reinterpret_cast<uint*>(o + 384) = f2bf(acc[3][0]) | (f2bf(acc[3][1]) << 16);
}

// ---------------- GEMM: out[n x 128] = agg_bf[n x 512] @ W2 + bias, MFMA, no LDS ----------------

__global__ void __launch_bounds__(256) gemm_kernel(
    const u16* __restrict__ aggbf, const u16* __restrict__ W2p,
    const float* __restrict__ bias, float* __restrict__ out, int n) {
    const int w = threadIdx.x >> 6, l = threadIdx.x & 63;
    const int r0 = blockIdx.x * 128 + w * 32;
    int ra = r0 + (l & 15);
    int rb = ra + 16;
    if (ra > n - 1) ra = n - 1;
    if (rb > n - 1) rb = n - 1;
    const u16* pa = aggbf + ((size_t)ra << 9) + ((l >> 4) << 3);
    const u16* pb = aggbf + ((size_t)rb << 9) + ((l >> 4) << 3);
    const u16* wp = W2p + ((size_t)l << 3);

    f32x4 acc[2][8];
    #pragma unroll
    for (int m = 0; m < 2; ++m)
        #pragma unroll
        for (int nf = 0; nf < 8; ++nf)
            acc[m][nf] = (f32x4){0.f, 0.f, 0.f, 0.f};

    #pragma unroll 2
    for (int ks = 0; ks < 16; ++ks) {
        bf16x8 a0 = *reinterpret_cast<const bf16x8*>(pa + ks * 32);
        bf16x8 a1 = *reinterpret_cast<const bf16x8*>(pb + ks * 32);
        #pragma unroll
        for (int nf = 0; nf < 8; ++nf) {
            bf16x8 bfr = *reinterpret_cast<const bf16x8*>(wp + (((nf << 4) + ks) << 9));
            acc[0][nf] = __builtin_amdgcn_mfma_f32_16x16x32_bf16(a0, bfr, acc[0][nf], 0, 0, 0);
            acc[1][nf] = __builtin_amdgcn_mfma_f32_16x16x32_bf16(a1, bfr, acc[1][nf], 0, 0, 0);
        }
    }

    const int cq = l >> 4;     // row quadrant
    const int cr = l & 15;     // output feature within frag
    #pragma unroll
    for (int nf = 0; nf < 8; ++nf) {
        float bv = bias[(nf << 4) + cr];
        #pragma unroll
        for (int m = 0; m < 2; ++m) {
            #pragma unroll
            for (int rg = 0; rg < 4; ++rg) {
                int rowi = r0 + m * 16 + cq * 4 + rg;
                if (rowi < n)
                    out[(size_t)rowi * OUT_F + (nf << 4) + cr] = acc[m][nf][rg] + bv;
            }
        }
    }
}

// ---------------- launch ----------------

extern "C" void kernel_launch(void* const* d_in, const int* in_sizes, int n_in,
                              void* d_out, int out_size, void* d_ws, size_t ws_size,
                              hipStream_t stream) {
    const float* x      = (const float*)d_in[0];
    const int*   edge   = (const int*)d_in[1];
    const float* weight = (const float*)d_in[2];
    const float* bias   = (const float*)d_in[3];
    const float* mu     = (const float*)d_in[4];
    const float* sig    = (const float*)d_in[5];
    float* out = (float*)d_out;

    const int n = in_sizes[0] / IN_F;
    const int E = in_sizes[1] / 2;
    const int* row = edge;
    const int* col = edge + E;

    char* ws = (char*)d_ws;
    size_t off = 0;
    auto alloc = [&](size_t bytes) {
        size_t o = off;
        off = (off + bytes + 255) & ~(size_t)255;
        return o;
    };
    u16*    xbf        = (u16*)(ws + alloc((size_t)n * IN_F * 2));
    float4* dom        = (float4*)(ws + alloc((size_t)n * 16));
    int*    col_sorted = (int*)(ws + alloc((size_t)E * 4));
    u16*    aggbf      = (u16*)(ws + alloc((size_t)n * KER * IN_F * 2));
    u16*    W2p        = (u16*)(ws + alloc((size_t)KER * IN_F * OUT_F * 2));
    int*    counts     = (int*)(ws + alloc((size_t)n * 4));
    int*    row_ptr    = (int*)(ws + alloc(((size_t)n + 1) * 4));
    int*    cursor     = (int*)(ws + alloc((size_t)n * 4));
    int*    bsum       = (int*)(ws + alloc(1024 * 4));
    float*  kc         = (float*)(ws + alloc(32 * 4));
    if (off > ws_size) return;  // insufficient workspace: fail visibly rather than corrupt

    const int nB1 = (n * 32 + 255) / 256;
    const int nB2 = 32;
    const int nB3 = (n + 255) / 256;
    prep_kernel<<<nB1 + nB2 + nB3, 256, 0, stream>>>(x, weight, mu, sig, n, xbf, dom, W2p,
                                                     counts, kc, nB1, nB2);
    hist_kernel<<<(E + 255) / 256, 256, 0, stream>>>(row, E, counts);
    const int nb = (n + 1023) / 1024;   // 49 for n=50000; scanC requires nb <= 64
    scanA_kernel<<<nb, 1024, 0, stream>>>(counts, n, bsum);
    scanC_kernel<<<nb, 1024, 0, stream>>>(counts, n, bsum, row_ptr, cursor);
    scatter_kernel<<<(E + 255) / 256, 256, 0, stream>>>(row, col, E, cursor, col_sorted);
    agg_kernel<<<n, 64, 0, stream>>>(xbf, row_ptr, col_sorted, dom, kc, aggbf, n);
    gemm_kernel<<<(n + 127) / 128, 256, 0, stream>>>(aggbf, W2p, bias, out, n);
}

// Round 5
// 316.756 us; speedup vs baseline: 1.3643x; 1.3643x over previous
//
#include <hip/hip_runtime.h>

#define IN_F 128
#define OUT_F 128
#define KER 4
#define CHUNK 16384

typedef unsigned int uint;
typedef unsigned short u16;
typedef __attribute__((ext_vector_type(8))) short bf16x8;
typedef __attribute__((ext_vector_type(4))) float f32x4;

__device__ __forceinline__ uint f2bf(float f) {
    uint u = __float_as_uint(f);
    u += 0x7fffu + ((u >> 16) & 1u);
    return u >> 16;
}

// ---- fused prep: x->bf16 + dom extract | W repack to frag layout | kernel consts ----

__global__ void __launch_bounds__(256) prep_kernel(
    const float* __restrict__ x, const float* __restrict__ weight,
    const float* __restrict__ mu, const float* __restrict__ sig, int n,
    u16* __restrict__ xbf, float4* __restrict__ dom, u16* __restrict__ W2p,
    float* __restrict__ kc, int nB1, int nB2) {
    const int b = blockIdx.x;
    if (b < nB1) {
        int t = b * 256 + threadIdx.x;               // one thread = 4 floats
        if (t < n * 32) {
            float4 v = *reinterpret_cast<const float4*>(x + (size_t)t * 4);
            uint2 o;
            o.x = f2bf(v.x) | (f2bf(v.y) << 16);
            o.y = f2bf(v.z) | (f2bf(v.w) << 16);
            *reinterpret_cast<uint2*>(xbf + (size_t)t * 4) = o;
            if ((t & 31) == 0) dom[t >> 5] = make_float4(v.x, v.y, v.z, 0.f);
        }
    } else if (b < nB1 + nB2) {
        int t = (b - nB1) * 256 + threadIdx.x;       // 0..8191, one B-fragment-lane each
        if (t < 8192) {
            int lane = t & 63;
            int nfks = t >> 6;                        // (nf*16 + ks)
            int ks = nfks & 15, nf = nfks >> 4;
            int f = nf * 16 + (lane & 15);
            int kbase = ks * 32 + ((lane >> 4) << 3);
            uint pk[4];
            #pragma unroll
            for (int jj = 0; jj < 4; ++jj) {
                int k0 = kbase + jj * 2;
                int c0 = k0 & 127, q0 = k0 >> 7;
                int k1 = k0 + 1;
                int c1 = k1 & 127, q1 = k1 >> 7;
                uint lo = f2bf(weight[((size_t)c0 * OUT_F + f) * KER + q0]);
                uint hi = f2bf(weight[((size_t)c1 * OUT_F + f) * KER + q1]);
                pk[jj] = lo | (hi << 16);
            }
            *reinterpret_cast<uint4*>(W2p + (size_t)t * 8) =
                make_uint4(pk[0], pk[1], pk[2], pk[3]);
        }
    } else {
        // v_k = exp(A_k + B_k*S + C0_k*d0 + C1_k*d1 + C2_k*d2), S = |d|^2
        if (threadIdx.x < KER) {
            int k = threadIdx.x;
            float sg = sig[k];
            float m0 = mu[k], m1 = mu[KER + k], m2 = mu[2 * KER + k];
            kc[k * 5 + 0] = -0.5f * sg * (m0 * m0 + m1 * m1 + m2 * m2);
            kc[k * 5 + 1] = -0.5f * sg;
            kc[k * 5 + 2] = sg * m0;
            kc[k * 5 + 3] = sg * m1;
            kc[k * 5 + 4] = sg * m2;
        }
    }
}

// ---------------- CSR build: deterministic atomic-free counting sort ----------------

// hist[chunk][row] (u16): per-chunk row histogram via LDS (2 u16 counters packed/u32).
// Grid = nchunk * 4; block (ch, q) covers rows [q*wq, min(n,(q+1)*wq)).
__global__ void __launch_bounds__(1024) hist_kernel(
    const int* __restrict__ row, int E, int n, int nchunk,
    u16* __restrict__ hist) {
    extern __shared__ uint lds[];
    const int ch = blockIdx.x >> 2, q = blockIdx.x & 3;
    const int wq = (n + 3) >> 2;
    const int r_lo = q * wq;
    const int r_hi = min(n, r_lo + wq);
    const int width = r_hi - r_lo;
    const int words = (width + 1) >> 1;
    for (int i = threadIdx.x; i < words; i += 1024) lds[i] = 0;
    __syncthreads();
    const int base = ch * CHUNK;
    const int lim = min(base + CHUNK, E);
    for (int e = base + threadIdx.x; e < lim; e += 1024) {
        int r = row[e];
        if (r >= r_lo && r < r_hi) {
            int rr = r - r_lo;
            atomicAdd(&lds[rr >> 1], 1u << ((rr & 1) << 4));
        }
    }
    __syncthreads();
    uint* out32 = (uint*)(hist + (size_t)ch * n + r_lo);
    for (int i = threadIdx.x; i < words; i += 1024) out32[i] = lds[i];
}

// Per-row running sum across chunks: bases[ch][r] = #row-r edges in chunks < ch; counts[r]=deg(r)
__global__ void __launch_bounds__(256) colscan_kernel(
    const u16* __restrict__ hist, u16* __restrict__ bases,
    int* __restrict__ counts, int n, int nchunk) {
    int r = blockIdx.x * 256 + threadIdx.x;
    if (r >= n) return;
    uint acc = 0;
    for (int b = 0; b < nchunk; ++b) {
        uint t = hist[(size_t)b * n + r];
        bases[(size_t)b * n + r] = (u16)acc;
        acc += t;
    }
    counts[r] = (int)acc;
}

__global__ void scanA_kernel(const int* __restrict__ counts, int n, int* __restrict__ bsum) {
    __shared__ int wsum[16];
    int i = blockIdx.x * 1024 + threadIdx.x;
    int lane = threadIdx.x & 63, wv = threadIdx.x >> 6;
    int v = (i < n) ? counts[i] : 0;
    #pragma unroll
    for (int off = 32; off > 0; off >>= 1) v += __shfl_down(v, off, 64);
    if (lane == 0) wsum[wv] = v;
    __syncthreads();
    if (threadIdx.x == 0) {
        int t = 0;
        #pragma unroll
        for (int q = 0; q < 16; ++q) t += wsum[q];
        bsum[blockIdx.x] = t;
    }
}

// scanC with folded block-offset reduction (requires gridDim <= 64, i.e. n <= 65536)
__global__ void scanC_kernel(const int* __restrict__ counts, int n, const int* __restrict__ bsum,
                             int* __restrict__ row_ptr) {
    __shared__ int wsum[16];
    __shared__ int s_boff;
    const int tid = threadIdx.x, lane = tid & 63, wv = tid >> 6;
    const int i = blockIdx.x * 1024 + tid;
    if (tid < 64) {
        int v = (tid < blockIdx.x) ? bsum[tid] : 0;
        #pragma unroll
        for (int off = 32; off > 0; off >>= 1) v += __shfl_down(v, off, 64);
        if (tid == 0) s_boff = v;
    }
    int v = (i < n) ? counts[i] : 0;
    int s = v;
    #pragma unroll
    for (int off = 1; off < 64; off <<= 1) {
        int t = __shfl_up(s, off, 64);
        if (lane >= off) s += t;
    }
    if (lane == 63) wsum[wv] = s;
    __syncthreads();
    if (wv == 0 && lane < 16) {
        int w = wsum[lane];
        #pragma unroll
        for (int off = 1; off < 16; off <<= 1) {
            int t = __shfl_up(w, off, 64);
            if (lane >= off) w += t;
        }
        wsum[lane] = w;
    }
    __syncthreads();
    int base = s_boff + (wv ? wsum[wv - 1] : 0);
    int incl = base + s;
    if (i < n) row_ptr[i + 1] = incl;
    if (i == 0) row_ptr[0] = 0;
}

// place: grid = nchunk*8; block (ch, x) handles rows in XCD-slot x's range [x*wp, (x+1)*wp).
// With blockIdx%8 -> XCD round-robin, each output region is written by ONE XCD's L2 -> merges.
// pos = row_ptr[r] + bases[ch][r] + intra-chunk LDS rank  (deterministic position set, no global atomics)
__global__ void __launch_bounds__(1024) place_kernel(
    const int* __restrict__ row, const int* __restrict__ col, int E, int n,
    const u16* __restrict__ bases, const int* __restrict__ row_ptr,
    u16* __restrict__ col_sorted) {
    extern __shared__ uint lds[];
    const int ch = blockIdx.x >> 3, x = blockIdx.x & 7;
    const int wp = (n + 7) >> 3;
    const int r_lo = x * wp;
    const int r_hi = min(n, r_lo + wp);
    const int width = r_hi - r_lo;
    const int words = (width + 1) >> 1;
    for (int i = threadIdx.x; i < words; i += 1024) lds[i] = 0;
    __syncthreads();
    const int base = ch * CHUNK;
    const int lim = min(base + CHUNK, E);
    const u16* br = bases + (size_t)ch * n;
    for (int e = base + threadIdx.x; e < lim; e += 1024) {
        int r = row[e];
        int c = col[e];
        if (r >= r_lo && r < r_hi) {
            int rr = r - r_lo;
            uint sh = (rr & 1) << 4;
            uint old = atomicAdd(&lds[rr >> 1], 1u << sh);
            int rank = (int)((old >> sh) & 0xffffu);
            int pos = row_ptr[r] + (int)br[r] + rank;
            col_sorted[pos] = (u16)c;
        }
    }
}

// ---- Aggregation: one wave per row; recompute gaussian values from dom; 4-edge MLP ----

__global__ void __launch_bounds__(64) agg_kernel(
    const u16* __restrict__ xbf, const int* __restrict__ row_ptr,
    const u16* __restrict__ col_sorted, const float4* __restrict__ dom,
    const float* __restrict__ kc, u16* __restrict__ aggbf, int n) {
    const int i = blockIdx.x;
    const int l = threadIdx.x;
    const int start = row_ptr[i];
    const int end   = row_ptr[i + 1];
    const float4 dr = dom[i];
    float A[4], B[4], C0[4], C1[4], C2[4];
    #pragma unroll
    for (int k = 0; k < 4; ++k) {
        A[k]  = kc[k * 5 + 0];
        B[k]  = kc[k * 5 + 1];
        C0[k] = kc[k * 5 + 2];
        C1[k] = kc[k * 5 + 3];
        C2[k] = kc[k * 5 + 4];
    }

    float acc[4][2];
    #pragma unroll
    for (int k = 0; k < 4; ++k) { acc[k][0] = 0.f; acc[k][1] = 0.f; }

    auto body = [&](float qx, float qy, float qz, uint xp) {
        float d0 = dr.x - qx, d1 = dr.y - qy, d2 = dr.z - qz;
        float S = fmaf(d2, d2, fmaf(d1, d1, d0 * d0));
        float x0 = __uint_as_float(xp << 16);
        float x1 = __uint_as_float(xp & 0xffff0000u);
        #pragma unroll
        for (int k = 0; k < 4; ++k) {
            float t = fmaf(B[k], S, A[k]);
            t = fmaf(C0[k], d0, t);
            t = fmaf(C1[k], d1, t);
            t = fmaf(C2[k], d2, t);
            float v = __expf(t);
            acc[k][0] = fmaf(v, x0, acc[k][0]);
            acc[k][1] = fmaf(v, x1, acc[k][1]);
        }
    };

    int j = start;
    for (; j + 4 <= end; j += 4) {
        int c0 = col_sorted[j + 0];
        int c1 = col_sorted[j + 1];
        int c2 = col_sorted[j + 2];
        int c3 = col_sorted[j + 3];
        float4 q0 = dom[c0];
        float4 q1 = dom[c1];
        float4 q2 = dom[c2];
        float4 q3 = dom[c3];
        uint xp0 = *reinterpret_cast<const uint*>(xbf + ((size_t)c0 << 7) + (l << 1));
        uint xp1 = *reinterpret_cast<const uint*>(xbf + ((size_t)c1 << 7) + (l << 1));
        uint xp2 = *reinterpret_cast<const uint*>(xbf + ((size_t)c2 << 7) + (l << 1));
        uint xp3 = *reinterpret_cast<const uint*>(xbf + ((size_t)c3 << 7) + (l << 1));
        body(q0.x, q0.y, q0.z, xp0);
        body(q1.x, q1.y, q1.z, xp1);
        body(q2.x, q2.y, q2.z, xp2);
        body(q3.x, q3.y, q3.z, xp3);
    }
    for (; j < end; ++j) {
        int c = col_sorted[j];
        float4 q = dom[c];
        uint xp = *reinterpret_cast<const uint*>(xbf + ((size_t)c << 7) + (l << 1));
        body(q.x, q.y, q.z, xp);
    }

    u16* o = aggbf + ((size_t)i << 9) + (l << 1);
    *reinterpret_cast<uint*>(o +   0) = f2bf(acc[0][0]) | (f2bf(acc[0][1]) << 16);
    *reinterpret_cast<uint*>(o + 128) = f2bf(acc[1][0]) | (f2bf(acc[1][1]) << 16);
    *reinterpret_cast<uint*>(o + 256) = f2bf(acc[2][0]) | (f2bf(acc[2][1]) << 16);
    *reinterpret_cast<uint*>(o + 384) = f2bf(acc[3][0]) | (f2bf(acc[3][1]) << 16);
}

// ---------------- GEMM: out[n x 128] = agg_bf[n x 512] @ W2 + bias, MFMA, no LDS ----------------

__global__ void __launch_bounds__(256) gemm_kernel(
    const u16* __restrict__ aggbf, const u16* __restrict__ W2p,
    const float* __restrict__ bias, float* __restrict__ out, int n) {
    const int w = threadIdx.x >> 6, l = threadIdx.x & 63;
    const int r0 = blockIdx.x * 128 + w * 32;
    int ra = r0 + (l & 15);
    int rb = ra + 16;
    if (ra > n - 1) ra = n - 1;
    if (rb > n - 1) rb = n - 1;
    const u16* pa = aggbf + ((size_t)ra << 9) + ((l >> 4) << 3);
    const u16* pb = aggbf + ((size_t)rb << 9) + ((l >> 4) << 3);
    const u16* wp = W2p + ((size_t)l << 3);

    f32x4 acc[2][8];
    #pragma unroll
    for (int m = 0; m < 2; ++m)
        #pragma unroll
        for (int nf = 0; nf < 8; ++nf)
            acc[m][nf] = (f32x4){0.f, 0.f, 0.f, 0.f};

    #pragma unroll 2
    for (int ks = 0; ks < 16; ++ks) {
        bf16x8 a0 = *reinterpret_cast<const bf16x8*>(pa + ks * 32);
        bf16x8 a1 = *reinterpret_cast<const bf16x8*>(pb + ks * 32);
        #pragma unroll
        for (int nf = 0; nf < 8; ++nf) {
            bf16x8 bfr = *reinterpret_cast<const bf16x8*>(wp + (((nf << 4) + ks) << 9));
            acc[0][nf] = __builtin_amdgcn_mfma_f32_16x16x32_bf16(a0, bfr, acc[0][nf], 0, 0, 0);
            acc[1][nf] = __builtin_amdgcn_mfma_f32_16x16x32_bf16(a1, bfr, acc[1][nf], 0, 0, 0);
        }
    }

    const int cq = l >> 4;     // row quadrant
    const int cr = l & 15;     // output feature within frag
    #pragma unroll
    for (int nf = 0; nf < 8; ++nf) {
        float bv = bias[(nf << 4) + cr];
        #pragma unroll
        for (int m = 0; m < 2; ++m) {
            #pragma unroll
            for (int rg = 0; rg < 4; ++rg) {
                int rowi = r0 + m * 16 + cq * 4 + rg;
                if (rowi < n)
                    out[(size_t)rowi * OUT_F + (nf << 4) + cr] = acc[m][nf][rg] + bv;
            }
        }
    }
}

// ---------------- launch ----------------

extern "C" void kernel_launch(void* const* d_in, const int* in_sizes, int n_in,
                              void* d_out, int out_size, void* d_ws, size_t ws_size,
                              hipStream_t stream) {
    const float* x      = (const float*)d_in[0];
    const int*   edge   = (const int*)d_in[1];
    const float* weight = (const float*)d_in[2];
    const float* bias   = (const float*)d_in[3];
    const float* mu     = (const float*)d_in[4];
    const float* sig    = (const float*)d_in[5];
    float* out = (float*)d_out;

    const int n = in_sizes[0] / IN_F;
    const int E = in_sizes[1] / 2;
    const int* row = edge;
    const int* col = edge + E;
    const int nchunk = (E + CHUNK - 1) / CHUNK;

    char* ws = (char*)d_ws;
    size_t off = 0;
    auto alloc = [&](size_t bytes) {
        size_t o = off;
        off = (off + bytes + 255) & ~(size_t)255;
        return o;
    };
    u16*    xbf        = (u16*)(ws + alloc((size_t)n * IN_F * 2));
    float4* dom        = (float4*)(ws + alloc((size_t)n * 16));
    u16*    col_sorted = (u16*)(ws + alloc((size_t)E * 2));
    u16*    aggbf      = (u16*)(ws + alloc((size_t)n * KER * IN_F * 2));
    u16*    W2p        = (u16*)(ws + alloc((size_t)KER * IN_F * OUT_F * 2));
    u16*    hist       = (u16*)(ws + alloc((size_t)nchunk * n * 2));
    u16*    bases      = (u16*)(ws + alloc((size_t)nchunk * n * 2));
    int*    counts     = (int*)(ws + alloc((size_t)n * 4));
    int*    row_ptr    = (int*)(ws + alloc(((size_t)n + 1) * 4));
    int*    bsum       = (int*)(ws + alloc(1024 * 4));
    float*  kc         = (float*)(ws + alloc(32 * 4));
    if (off > ws_size) return;  // insufficient workspace: fail visibly rather than corrupt

    const int nB1 = (n * 32 + 255) / 256;
    const int nB2 = 32;
    prep_kernel<<<nB1 + nB2 + 1, 256, 0, stream>>>(x, weight, mu, sig, n, xbf, dom, W2p,
                                                   kc, nB1, nB2);
    const int wq = (n + 3) >> 2;
    const size_t hist_lds = (size_t)((wq + 1) >> 1) * 4;
    hist_kernel<<<nchunk * 4, 1024, hist_lds, stream>>>(row, E, n, nchunk, hist);
    colscan_kernel<<<(n + 255) / 256, 256, 0, stream>>>(hist, bases, counts, n, nchunk);
    const int nb = (n + 1023) / 1024;   // 49 for n=50000; scanC requires nb <= 64
    scanA_kernel<<<nb, 1024, 0, stream>>>(counts, n, bsum);
    scanC_kernel<<<nb, 1024, 0, stream>>>(counts, n, bsum, row_ptr);
    const int wp = (n + 7) >> 3;
    const size_t place_lds = (size_t)((wp + 1) >> 1) * 4;
    place_kernel<<<nchunk * 8, 1024, place_lds, stream>>>(row, col, E, n, bases, row_ptr,
                                                          col_sorted);
    agg_kernel<<<n, 64, 0, stream>>>(xbf, row_ptr, col_sorted, dom, kc, aggbf, n);
    gemm_kernel<<<(n + 127) / 128, 256, 0, stream>>>(aggbf, W2p, bias, out, n);
}

// Round 6
// 295.616 us; speedup vs baseline: 1.4619x; 1.0715x over previous
//
#include <hip/hip_runtime.h>

#define IN_F 128
#define OUT_F 128
#define KER 4
#define CHUNK 16384

typedef unsigned int uint;
typedef unsigned short u16;
typedef __attribute__((ext_vector_type(8))) short bf16x8;
typedef __attribute__((ext_vector_type(4))) float f32x4;

__device__ __forceinline__ uint f2bf(float f) {
    uint u = __float_as_uint(f);
    u += 0x7fffu + ((u >> 16) & 1u);
    return u >> 16;
}

// ---- fused prep: x->bf16 + dom extract | W repack to frag layout | kernel consts ----

__global__ void __launch_bounds__(256) prep_kernel(
    const float* __restrict__ x, const float* __restrict__ weight,
    const float* __restrict__ mu, const float* __restrict__ sig, int n,
    u16* __restrict__ xbf, float4* __restrict__ dom, u16* __restrict__ W2p,
    float* __restrict__ kc, int nB1, int nB2) {
    const int b = blockIdx.x;
    if (b < nB1) {
        int t = b * 256 + threadIdx.x;               // one thread = 4 floats
        if (t < n * 32) {
            float4 v = *reinterpret_cast<const float4*>(x + (size_t)t * 4);
            uint2 o;
            o.x = f2bf(v.x) | (f2bf(v.y) << 16);
            o.y = f2bf(v.z) | (f2bf(v.w) << 16);
            *reinterpret_cast<uint2*>(xbf + (size_t)t * 4) = o;
            if ((t & 31) == 0) dom[t >> 5] = make_float4(v.x, v.y, v.z, 0.f);
        }
    } else if (b < nB1 + nB2) {
        int t = (b - nB1) * 256 + threadIdx.x;       // 0..8191, one B-fragment-lane each
        if (t < 8192) {
            int lane = t & 63;
            int nfks = t >> 6;                        // (nf*16 + ks)
            int ks = nfks & 15, nf = nfks >> 4;
            int f = nf * 16 + (lane & 15);
            int kbase = ks * 32 + ((lane >> 4) << 3);
            uint pk[4];
            #pragma unroll
            for (int jj = 0; jj < 4; ++jj) {
                int k0 = kbase + jj * 2;
                int c0 = k0 & 127, q0 = k0 >> 7;
                int k1 = k0 + 1;
                int c1 = k1 & 127, q1 = k1 >> 7;
                uint lo = f2bf(weight[((size_t)c0 * OUT_F + f) * KER + q0]);
                uint hi = f2bf(weight[((size_t)c1 * OUT_F + f) * KER + q1]);
                pk[jj] = lo | (hi << 16);
            }
            *reinterpret_cast<uint4*>(W2p + (size_t)t * 8) =
                make_uint4(pk[0], pk[1], pk[2], pk[3]);
        }
    } else {
        // v_k = exp(A_k + B_k*S + C0_k*d0 + C1_k*d1 + C2_k*d2), S = |d|^2
        if (threadIdx.x < KER) {
            int k = threadIdx.x;
            float sg = sig[k];
            float m0 = mu[k], m1 = mu[KER + k], m2 = mu[2 * KER + k];
            kc[k * 5 + 0] = -0.5f * sg * (m0 * m0 + m1 * m1 + m2 * m2);
            kc[k * 5 + 1] = -0.5f * sg;
            kc[k * 5 + 2] = sg * m0;
            kc[k * 5 + 3] = sg * m1;
            kc[k * 5 + 4] = sg * m2;
        }
    }
}

// ---------------- CSR build: deterministic atomic-free counting sort ----------------

// hist[chunk][row] (u16): per-chunk row histogram via LDS (2 u16 counters packed/u32).
// Grid = nchunk * 4; block (ch, q) covers rows [q*wq, min(n,(q+1)*wq)).
__global__ void __launch_bounds__(1024) hist_kernel(
    const int* __restrict__ row, int E, int n, int nchunk,
    u16* __restrict__ hist) {
    extern __shared__ uint lds[];
    const int ch = blockIdx.x >> 2, q = blockIdx.x & 3;
    const int wq = (n + 3) >> 2;
    const int r_lo = q * wq;
    const int r_hi = min(n, r_lo + wq);
    const int width = r_hi - r_lo;
    const int words = (width + 1) >> 1;
    for (int i = threadIdx.x; i < words; i += 1024) lds[i] = 0;
    __syncthreads();
    const int base = ch * CHUNK;
    const int lim = min(base + CHUNK, E);
    for (int e = base + threadIdx.x; e < lim; e += 1024) {
        int r = row[e];
        if (r >= r_lo && r < r_hi) {
            int rr = r - r_lo;
            atomicAdd(&lds[rr >> 1], 1u << ((rr & 1) << 4));
        }
    }
    __syncthreads();
    uint* out32 = (uint*)(hist + (size_t)ch * n + r_lo);
    for (int i = threadIdx.x; i < words; i += 1024) out32[i] = lds[i];
}

// Per-row running sum across chunks: bases[ch][r] = #row-r edges in chunks < ch; counts[r]=deg(r)
__global__ void __launch_bounds__(256) colscan_kernel(
    const u16* __restrict__ hist, u16* __restrict__ bases,
    int* __restrict__ counts, int n, int nchunk) {
    int r = blockIdx.x * 256 + threadIdx.x;
    if (r >= n) return;
    uint acc = 0;
    for (int b = 0; b < nchunk; ++b) {
        uint t = hist[(size_t)b * n + r];
        bases[(size_t)b * n + r] = (u16)acc;
        acc += t;
    }
    counts[r] = (int)acc;
}

__global__ void scanA_kernel(const int* __restrict__ counts, int n, int* __restrict__ bsum) {
    __shared__ int wsum[16];
    int i = blockIdx.x * 1024 + threadIdx.x;
    int lane = threadIdx.x & 63, wv = threadIdx.x >> 6;
    int v = (i < n) ? counts[i] : 0;
    #pragma unroll
    for (int off = 32; off > 0; off >>= 1) v += __shfl_down(v, off, 64);
    if (lane == 0) wsum[wv] = v;
    __syncthreads();
    if (threadIdx.x == 0) {
        int t = 0;
        #pragma unroll
        for (int q = 0; q < 16; ++q) t += wsum[q];
        bsum[blockIdx.x] = t;
    }
}

// scanC with folded block-offset reduction (requires gridDim <= 64, i.e. n <= 65536)
__global__ void scanC_kernel(const int* __restrict__ counts, int n, const int* __restrict__ bsum,
                             int* __restrict__ row_ptr) {
    __shared__ int wsum[16];
    __shared__ int s_boff;
    const int tid = threadIdx.x, lane = tid & 63, wv = tid >> 6;
    const int i = blockIdx.x * 1024 + tid;
    if (tid < 64) {
        int v = (tid < blockIdx.x) ? bsum[tid] : 0;
        #pragma unroll
        for (int off = 32; off > 0; off >>= 1) v += __shfl_down(v, off, 64);
        if (tid == 0) s_boff = v;
    }
    int v = (i < n) ? counts[i] : 0;
    int s = v;
    #pragma unroll
    for (int off = 1; off < 64; off <<= 1) {
        int t = __shfl_up(s, off, 64);
        if (lane >= off) s += t;
    }
    if (lane == 63) wsum[wv] = s;
    __syncthreads();
    if (wv == 0 && lane < 16) {
        int w = wsum[lane];
        #pragma unroll
        for (int off = 1; off < 16; off <<= 1) {
            int t = __shfl_up(w, off, 64);
            if (lane >= off) w += t;
        }
        wsum[lane] = w;
    }
    __syncthreads();
    int base = s_boff + (wv ? wsum[wv - 1] : 0);
    int incl = base + s;
    if (i < n) row_ptr[i + 1] = incl;
    if (i == 0) row_ptr[0] = 0;
}

// place: grid = nchunk*8; block (ch, x) owns rows [x*wp, (x+1)*wp) -> XCD-local write region.
// Computes the 4 gaussian values LANE-PARALLEL (one edge/thread) and writes 16B rec
// {v01, v23, col, 0} at pos = row_ptr[r] + bases[ch][r] + intra-chunk LDS rank.
__global__ void __launch_bounds__(1024) place_kernel(
    const int* __restrict__ row, const int* __restrict__ col, int E, int n,
    const u16* __restrict__ bases, const int* __restrict__ row_ptr,
    const float4* __restrict__ dom, const float* __restrict__ kc,
    uint4* __restrict__ recs) {
    extern __shared__ uint lds[];
    const int ch = blockIdx.x >> 3, x = blockIdx.x & 7;
    const int wp = (n + 7) >> 3;
    const int r_lo = x * wp;
    const int r_hi = min(n, r_lo + wp);
    const int width = r_hi - r_lo;
    const int words = (width + 1) >> 1;
    for (int i = threadIdx.x; i < words; i += 1024) lds[i] = 0;
    __syncthreads();
    float A[4], B[4], C0[4], C1[4], C2[4];
    #pragma unroll
    for (int k = 0; k < 4; ++k) {
        A[k]  = kc[k * 5 + 0];
        B[k]  = kc[k * 5 + 1];
        C0[k] = kc[k * 5 + 2];
        C1[k] = kc[k * 5 + 3];
        C2[k] = kc[k * 5 + 4];
    }
    const int base = ch * CHUNK;
    const int lim = min(base + CHUNK, E);
    const u16* br = bases + (size_t)ch * n;
    for (int e = base + threadIdx.x; e < lim; e += 1024) {
        int r = row[e];
        if (r >= r_lo && r < r_hi) {
            int c = col[e];
            float4 dr = dom[r], dc = dom[c];
            float d0 = dr.x - dc.x, d1 = dr.y - dc.y, d2 = dr.z - dc.z;
            float S = fmaf(d2, d2, fmaf(d1, d1, d0 * d0));
            uint vb[4];
            #pragma unroll
            for (int k = 0; k < 4; ++k) {
                float t = fmaf(B[k], S, A[k]);
                t = fmaf(C0[k], d0, t);
                t = fmaf(C1[k], d1, t);
                t = fmaf(C2[k], d2, t);
                vb[k] = f2bf(__expf(t));
            }
            int rr = r - r_lo;
            uint sh = (rr & 1) << 4;
            uint old = atomicAdd(&lds[rr >> 1], 1u << sh);
            int rank = (int)((old >> sh) & 0xffffu);
            int pos = row_ptr[r] + (int)br[r] + rank;
            recs[pos] = make_uint4(vb[0] | (vb[1] << 16), vb[2] | (vb[3] << 16), (uint)c, 0u);
        }
    }
}

// ---- Aggregation: 4 rows/block (wave each); 14-op/edge body; 4-edge gather hoisting ----

__global__ void __launch_bounds__(256) agg_kernel(
    const u16* __restrict__ xbf, const int* __restrict__ row_ptr,
    const uint4* __restrict__ recs, u16* __restrict__ aggbf, int n) {
    const int w = threadIdx.x >> 6, l = threadIdx.x & 63;
    const int i = blockIdx.x * 4 + w;
    if (i >= n) return;
    const int start = row_ptr[i];
    const int end   = row_ptr[i + 1];

    float acc[4][2];
    #pragma unroll
    for (int k = 0; k < 4; ++k) { acc[k][0] = 0.f; acc[k][1] = 0.f; }

    auto body = [&](uint lo, uint hi, uint xp) {
        float x0 = __uint_as_float(xp << 16);
        float x1 = __uint_as_float(xp & 0xffff0000u);
        float v0 = __uint_as_float(lo << 16);
        float v1 = __uint_as_float(lo & 0xffff0000u);
        float v2 = __uint_as_float(hi << 16);
        float v3 = __uint_as_float(hi & 0xffff0000u);
        acc[0][0] = fmaf(v0, x0, acc[0][0]); acc[0][1] = fmaf(v0, x1, acc[0][1]);
        acc[1][0] = fmaf(v1, x0, acc[1][0]); acc[1][1] = fmaf(v1, x1, acc[1][1]);
        acc[2][0] = fmaf(v2, x0, acc[2][0]); acc[2][1] = fmaf(v2, x1, acc[2][1]);
        acc[3][0] = fmaf(v3, x0, acc[3][0]); acc[3][1] = fmaf(v3, x1, acc[3][1]);
    };

    int j = start;
    for (; j + 4 <= end; j += 4) {
        uint4 r0 = recs[j + 0];
        uint4 r1 = recs[j + 1];
        uint4 r2 = recs[j + 2];
        uint4 r3 = recs[j + 3];
        uint xp0 = *reinterpret_cast<const uint*>(xbf + ((size_t)r0.z << 7) + (l << 1));
        uint xp1 = *reinterpret_cast<const uint*>(xbf + ((size_t)r1.z << 7) + (l << 1));
        uint xp2 = *reinterpret_cast<const uint*>(xbf + ((size_t)r2.z << 7) + (l << 1));
        uint xp3 = *reinterpret_cast<const uint*>(xbf + ((size_t)r3.z << 7) + (l << 1));
        body(r0.x, r0.y, xp0);
        body(r1.x, r1.y, xp1);
        body(r2.x, r2.y, xp2);
        body(r3.x, r3.y, xp3);
    }
    for (; j < end; ++j) {
        uint4 rc = recs[j];
        uint xp = *reinterpret_cast<const uint*>(xbf + ((size_t)rc.z << 7) + (l << 1));
        body(rc.x, rc.y, xp);
    }

    u16* o = aggbf + ((size_t)i << 9) + (l << 1);
    *reinterpret_cast<uint*>(o +   0) = f2bf(acc[0][0]) | (f2bf(acc[0][1]) << 16);
    *reinterpret_cast<uint*>(o + 128) = f2bf(acc[1][0]) | (f2bf(acc[1][1]) << 16);
    *reinterpret_cast<uint*>(o + 256) = f2bf(acc[2][0]) | (f2bf(acc[2][1]) << 16);
    *reinterpret_cast<uint*>(o + 384) = f2bf(acc[3][0]) | (f2bf(acc[3][1]) << 16);
}

// ---------------- GEMM: out[n x 128] = agg_bf[n x 512] @ W2 + bias, MFMA, no LDS ----------------

__global__ void __launch_bounds__(256) gemm_kernel(
    const u16* __restrict__ aggbf, const u16* __restrict__ W2p,
    const float* __restrict__ bias, float* __restrict__ out, int n) {
    const int w = threadIdx.x >> 6, l = threadIdx.x & 63;
    const int r0 = blockIdx.x * 128 + w * 32;
    int ra = r0 + (l & 15);
    int rb = ra + 16;
    if (ra > n - 1) ra = n - 1;
    if (rb > n - 1) rb = n - 1;
    const u16* pa = aggbf + ((size_t)ra << 9) + ((l >> 4) << 3);
    const u16* pb = aggbf + ((size_t)rb << 9) + ((l >> 4) << 3);
    const u16* wp = W2p + ((size_t)l << 3);

    f32x4 acc[2][8];
    #pragma unroll
    for (int m = 0; m < 2; ++m)
        #pragma unroll
        for (int nf = 0; nf < 8; ++nf)
            acc[m][nf] = (f32x4){0.f, 0.f, 0.f, 0.f};

    #pragma unroll 2
    for (int ks = 0; ks < 16; ++ks) {
        bf16x8 a0 = *reinterpret_cast<const bf16x8*>(pa + ks * 32);
        bf16x8 a1 = *reinterpret_cast<const bf16x8*>(pb + ks * 32);
        #pragma unroll
        for (int nf = 0; nf < 8; ++nf) {
            bf16x8 bfr = *reinterpret_cast<const bf16x8*>(wp + (((nf << 4) + ks) << 9));
            acc[0][nf] = __builtin_amdgcn_mfma_f32_16x16x32_bf16(a0, bfr, acc[0][nf], 0, 0, 0);
            acc[1][nf] = __builtin_amdgcn_mfma_f32_16x16x32_bf16(a1, bfr, acc[1][nf], 0, 0, 0);
        }
    }

    const int cq = l >> 4;     // row quadrant
    const int cr = l & 15;     // output feature within frag
    #pragma unroll
    for (int nf = 0; nf < 8; ++nf) {
        float bv = bias[(nf << 4) + cr];
        #pragma unroll
        for (int m = 0; m < 2; ++m) {
            #pragma unroll
            for (int rg = 0; rg < 4; ++rg) {
                int rowi = r0 + m * 16 + cq * 4 + rg;
                if (rowi < n)
                    out[(size_t)rowi * OUT_F + (nf << 4) + cr] = acc[m][nf][rg] + bv;
            }
        }
    }
}

// ---------------- launch ----------------

extern "C" void kernel_launch(void* const* d_in, const int* in_sizes, int n_in,
                              void* d_out, int out_size, void* d_ws, size_t ws_size,
                              hipStream_t stream) {
    const float* x      = (const float*)d_in[0];
    const int*   edge   = (const int*)d_in[1];
    const float* weight = (const float*)d_in[2];
    const float* bias   = (const float*)d_in[3];
    const float* mu     = (const float*)d_in[4];
    const float* sig    = (const float*)d_in[5];
    float* out = (float*)d_out;

    const int n = in_sizes[0] / IN_F;
    const int E = in_sizes[1] / 2;
    const int* row = edge;
    const int* col = edge + E;
    const int nchunk = (E + CHUNK - 1) / CHUNK;

    char* ws = (char*)d_ws;
    size_t off = 0;
    auto alloc = [&](size_t bytes) {
        size_t o = off;
        off = (off + bytes + 255) & ~(size_t)255;
        return o;
    };
    u16*    xbf        = (u16*)(ws + alloc((size_t)n * IN_F * 2));
    float4* dom        = (float4*)(ws + alloc((size_t)n * 16));
    uint4*  recs       = (uint4*)(ws + alloc((size_t)E * 16));
    u16*    aggbf      = (u16*)(ws + alloc((size_t)n * KER * IN_F * 2));
    u16*    W2p        = (u16*)(ws + alloc((size_t)KER * IN_F * OUT_F * 2));
    u16*    hist       = (u16*)(ws + alloc((size_t)nchunk * n * 2));
    u16*    bases      = (u16*)(ws + alloc((size_t)nchunk * n * 2));
    int*    counts     = (int*)(ws + alloc((size_t)n * 4));
    int*    row_ptr    = (int*)(ws + alloc(((size_t)n + 1) * 4));
    int*    bsum       = (int*)(ws + alloc(1024 * 4));
    float*  kc         = (float*)(ws + alloc(32 * 4));
    if (off > ws_size) return;  // insufficient workspace: fail visibly rather than corrupt

    const int nB1 = (n * 32 + 255) / 256;
    const int nB2 = 32;
    prep_kernel<<<nB1 + nB2 + 1, 256, 0, stream>>>(x, weight, mu, sig, n, xbf, dom, W2p,
                                                   kc, nB1, nB2);
    const int wq = (n + 3) >> 2;
    const size_t hist_lds = (size_t)((wq + 1) >> 1) * 4;
    hist_kernel<<<nchunk * 4, 1024, hist_lds, stream>>>(row, E, n, nchunk, hist);
    colscan_kernel<<<(n + 255) / 256, 256, 0, stream>>>(hist, bases, counts, n, nchunk);
    const int nb = (n + 1023) / 1024;   // 49 for n=50000; scanC requires nb <= 64
    scanA_kernel<<<nb, 1024, 0, stream>>>(counts, n, bsum);
    scanC_kernel<<<nb, 1024, 0, stream>>>(counts, n, bsum, row_ptr);
    const int wp = (n + 7) >> 3;
    const size_t place_lds = (size_t)((wp + 1) >> 1) * 4;
    place_kernel<<<nchunk * 8, 1024, place_lds, stream>>>(row, col, E, n, bases, row_ptr,
                                                          dom, kc, recs);
    agg_kernel<<<(n + 3) / 4, 256, 0, stream>>>(xbf, row_ptr, recs, aggbf, n);
    gemm_kernel<<<(n + 127) / 128, 256, 0, stream>>>(aggbf, W2p, bias, out, n);
}

// Round 7
// 281.860 us; speedup vs baseline: 1.5332x; 1.0488x over previous
//
#include <hip/hip_runtime.h>

#define IN_F 128
#define OUT_F 128
#define KER 4
#define CHUNK 32768

typedef unsigned int uint;
typedef unsigned short u16;
typedef __attribute__((ext_vector_type(8))) short bf16x8;
typedef __attribute__((ext_vector_type(4))) float f32x4;

__device__ __forceinline__ uint f2bf(float f) {
    uint u = __float_as_uint(f);
    u += 0x7fffu + ((u >> 16) & 1u);
    return u >> 16;
}

// ---- fused prep: x->bf16 + dom | W repack to frag layout | kernel consts + zero bsum ----

__global__ void __launch_bounds__(256) prep_kernel(
    const float* __restrict__ x, const float* __restrict__ weight,
    const float* __restrict__ mu, const float* __restrict__ sig, int n,
    u16* __restrict__ xbf, float4* __restrict__ dom, u16* __restrict__ W2p,
    float* __restrict__ kc, int* __restrict__ bsum, int nB1, int nB2) {
    const int b = blockIdx.x;
    if (b < nB1) {
        int t = b * 256 + threadIdx.x;               // one thread = 4 floats
        if (t < n * 32) {
            float4 v = *reinterpret_cast<const float4*>(x + (size_t)t * 4);
            uint2 o;
            o.x = f2bf(v.x) | (f2bf(v.y) << 16);
            o.y = f2bf(v.z) | (f2bf(v.w) << 16);
            *reinterpret_cast<uint2*>(xbf + (size_t)t * 4) = o;
            if ((t & 31) == 0) dom[t >> 5] = make_float4(v.x, v.y, v.z, 0.f);
        }
    } else if (b < nB1 + nB2) {
        int t = (b - nB1) * 256 + threadIdx.x;       // 0..8191, one B-fragment-lane each
        if (t < 8192) {
            int lane = t & 63;
            int nfks = t >> 6;                        // (nf*16 + ks)
            int ks = nfks & 15, nf = nfks >> 4;
            int f = nf * 16 + (lane & 15);
            int kbase = ks * 32 + ((lane >> 4) << 3);
            uint pk[4];
            #pragma unroll
            for (int jj = 0; jj < 4; ++jj) {
                int k0 = kbase + jj * 2;
                int c0 = k0 & 127, q0 = k0 >> 7;
                int k1 = k0 + 1;
                int c1 = k1 & 127, q1 = k1 >> 7;
                uint lo = f2bf(weight[((size_t)c0 * OUT_F + f) * KER + q0]);
                uint hi = f2bf(weight[((size_t)c1 * OUT_F + f) * KER + q1]);
                pk[jj] = lo | (hi << 16);
            }
            *reinterpret_cast<uint4*>(W2p + (size_t)t * 8) =
                make_uint4(pk[0], pk[1], pk[2], pk[3]);
        }
    } else {
        // v_k = exp(A_k + B_k*S + C0_k*d0 + C1_k*d1 + C2_k*d2), S = |d|^2
        if (threadIdx.x < KER) {
            int k = threadIdx.x;
            float sg = sig[k];
            float m0 = mu[k], m1 = mu[KER + k], m2 = mu[2 * KER + k];
            kc[k * 5 + 0] = -0.5f * sg * (m0 * m0 + m1 * m1 + m2 * m2);
            kc[k * 5 + 1] = -0.5f * sg;
            kc[k * 5 + 2] = sg * m0;
            kc[k * 5 + 3] = sg * m1;
            kc[k * 5 + 4] = sg * m2;
        }
        if (threadIdx.x >= 64 && threadIdx.x < 128) bsum[threadIdx.x - 64] = 0;
    }
}

// ---------------- CSR build: deterministic atomic-free counting sort ----------------

// hist[chunk][row] (u16) via LDS (2 u16 packed/u32). Grid = nchunk*2; block (ch,q)
// covers rows [q*wq, min(n,(q+1)*wq)), wq = (n+1)/2. Each edge is in-range exactly once.
__global__ void __launch_bounds__(1024) hist_kernel(
    const int* __restrict__ row, int E, int n,
    u16* __restrict__ hist) {
    extern __shared__ uint lds[];
    const int ch = blockIdx.x >> 1, q = blockIdx.x & 1;
    const int wq = (n + 1) >> 1;
    const int r_lo = q * wq;
    const int r_hi = min(n, r_lo + wq);
    const int width = r_hi - r_lo;
    const int words = (width + 1) >> 1;
    for (int i = threadIdx.x; i < words; i += 1024) lds[i] = 0;
    __syncthreads();
    const int base = ch * CHUNK;
    const int lim = min(base + CHUNK, E);
    #pragma unroll 4
    for (int e = base + threadIdx.x; e < lim; e += 1024) {
        int r = row[e];
        if (r >= r_lo && r < r_hi) {
            int rr = r - r_lo;
            atomicAdd(&lds[rr >> 1], 1u << ((rr & 1) << 4));
        }
    }
    __syncthreads();
    uint* out32 = (uint*)(hist + (size_t)ch * n + r_lo);
    for (int i = threadIdx.x; i < words; i += 1024) out32[i] = lds[i];
}

// Per-row running sum across chunks (bases, counts) + folded scanA (block-reduced bsum)
__global__ void __launch_bounds__(256) colscan_kernel(
    const u16* __restrict__ hist, u16* __restrict__ bases,
    int* __restrict__ counts, int* __restrict__ bsum, int n, int nchunk) {
    __shared__ int red[4];
    int r = blockIdx.x * 256 + threadIdx.x;
    uint acc = 0;
    if (r < n) {
        for (int b = 0; b < nchunk; ++b) {
            uint t = hist[(size_t)b * n + r];
            bases[(size_t)b * n + r] = (u16)acc;
            acc += t;
        }
        counts[r] = (int)acc;
    }
    int lane = threadIdx.x & 63, wv = threadIdx.x >> 6;
    int v = (r < n) ? (int)acc : 0;
    #pragma unroll
    for (int off = 32; off > 0; off >>= 1) v += __shfl_down(v, off, 64);
    if (lane == 0) red[wv] = v;
    __syncthreads();
    if (threadIdx.x == 0)
        atomicAdd(&bsum[blockIdx.x >> 2], red[0] + red[1] + red[2] + red[3]);
}

// scanC: row_ptr from counts (block offsets from bsum; needs gridDim <= 64) and
// posbase[ch][r] = row_ptr[r] + bases[ch][r]  (single-gather table for place)
__global__ void scanC_kernel(const int* __restrict__ counts, int n, const int* __restrict__ bsum,
                             const u16* __restrict__ bases, int* __restrict__ posbase,
                             int* __restrict__ row_ptr, int nchunk) {
    __shared__ int wsum[16];
    __shared__ int s_boff;
    const int tid = threadIdx.x, lane = tid & 63, wv = tid >> 6;
    const int i = blockIdx.x * 1024 + tid;
    if (tid < 64) {
        int v = (tid < blockIdx.x) ? bsum[tid] : 0;
        #pragma unroll
        for (int off = 32; off > 0; off >>= 1) v += __shfl_down(v, off, 64);
        if (tid == 0) s_boff = v;
    }
    int v = (i < n) ? counts[i] : 0;
    int s = v;
    #pragma unroll
    for (int off = 1; off < 64; off <<= 1) {
        int t = __shfl_up(s, off, 64);
        if (lane >= off) s += t;
    }
    if (lane == 63) wsum[wv] = s;
    __syncthreads();
    if (wv == 0 && lane < 16) {
        int w = wsum[lane];
        #pragma unroll
        for (int off = 1; off < 16; off <<= 1) {
            int t = __shfl_up(w, off, 64);
            if (lane >= off) w += t;
        }
        wsum[lane] = w;
    }
    __syncthreads();
    int base = s_boff + (wv ? wsum[wv - 1] : 0);
    int incl = base + s;
    if (i < n) {
        row_ptr[i + 1] = incl;
        int rp0 = incl - v;   // row_ptr[i]
        for (int ch = 0; ch < nchunk; ++ch)
            posbase[(size_t)ch * n + i] = rp0 + (int)bases[(size_t)ch * n + i];
    }
    if (i == 0) row_ptr[0] = 0;
}

// place: grid = nchunk*8; block (ch,x) owns rows [x*wp,(x+1)*wp) -> XCD-local write region.
// Lane-parallel gaussian values; 4-edge batches for gather MLP; single posbase gather.
__global__ void __launch_bounds__(1024) place_kernel(
    const int* __restrict__ row, const int* __restrict__ col, int E, int n,
    const int* __restrict__ posbase, const float4* __restrict__ dom,
    const float* __restrict__ kc, uint4* __restrict__ recs) {
    extern __shared__ uint lds[];
    const int ch = blockIdx.x >> 3, x = blockIdx.x & 7;
    const int wp = (n + 7) >> 3;
    const int r_lo = x * wp;
    const int r_hi = min(n, r_lo + wp);
    const int width = r_hi - r_lo;
    const int words = (width + 1) >> 1;
    for (int i = threadIdx.x; i < words; i += 1024) lds[i] = 0;
    __syncthreads();
    float A[4], B[4], C0[4], C1[4], C2[4];
    #pragma unroll
    for (int k = 0; k < 4; ++k) {
        A[k]  = kc[k * 5 + 0];
        B[k]  = kc[k * 5 + 1];
        C0[k] = kc[k * 5 + 2];
        C1[k] = kc[k * 5 + 3];
        C2[k] = kc[k * 5 + 4];
    }
    const int base = ch * CHUNK;
    const int lim = min(base + CHUNK, E);
    const int* pb = posbase + (size_t)ch * n;
    for (int e0 = base + threadIdx.x; e0 < lim; e0 += 4096) {
        int rr[4], cc[4];
        bool act[4];
        #pragma unroll
        for (int u = 0; u < 4; ++u) {
            int e = e0 + u * 1024;
            bool inb = e < lim;
            rr[u] = inb ? row[e] : 0;
            cc[u] = inb ? col[e] : 0;
            act[u] = inb && (rr[u] >= r_lo) && (rr[u] < r_hi);
        }
        float4 drv[4], dcv[4];
        #pragma unroll
        for (int u = 0; u < 4; ++u)
            if (act[u]) { drv[u] = dom[rr[u]]; dcv[u] = dom[cc[u]]; }
        #pragma unroll
        for (int u = 0; u < 4; ++u) {
            if (!act[u]) continue;
            float d0 = drv[u].x - dcv[u].x, d1 = drv[u].y - dcv[u].y, d2 = drv[u].z - dcv[u].z;
            float S = fmaf(d2, d2, fmaf(d1, d1, d0 * d0));
            uint vb[4];
            #pragma unroll
            for (int k = 0; k < 4; ++k) {
                float t = fmaf(B[k], S, A[k]);
                t = fmaf(C0[k], d0, t);
                t = fmaf(C1[k], d1, t);
                t = fmaf(C2[k], d2, t);
                vb[k] = f2bf(__expf(t));
            }
            int rl = rr[u] - r_lo;
            uint sh = (rl & 1) << 4;
            uint old = atomicAdd(&lds[rl >> 1], 1u << sh);
            int rank = (int)((old >> sh) & 0xffffu);
            int pos = pb[rr[u]] + rank;
            recs[pos] = make_uint4(vb[0] | (vb[1] << 16), vb[2] | (vb[3] << 16),
                                   (uint)cc[u], 0u);
        }
    }
}

// ---- Fused aggregation + GEMM: block = 16 rows; phase 1 agg -> swizzled LDS tile;
// ---- phase 2 MFMA vs W2p + bias epilogue. out[i][f] = sum_k agg[i][k*128+c] W2 + b.

__global__ void __launch_bounds__(256) aggemm_kernel(
    const u16* __restrict__ xbf, const int* __restrict__ row_ptr,
    const uint4* __restrict__ recs, const u16* __restrict__ W2p,
    const float* __restrict__ bias, float* __restrict__ out, int n) {
    __shared__ u16 tile[16 * 512];   // [row][kdim], XOR-swizzled: byte ^= ((row&7)<<4)
    const int w = threadIdx.x >> 6, l = threadIdx.x & 63;
    const int rbase = blockIdx.x * 16;

    // ---- phase 1: each wave aggregates 4 rows ----
    for (int q = 0; q < 4; ++q) {
        const int lr = w * 4 + q;
        const int i = rbase + lr;
        float acc[4][2];
        #pragma unroll
        for (int k = 0; k < 4; ++k) { acc[k][0] = 0.f; acc[k][1] = 0.f; }
        if (i < n) {
            const int start = row_ptr[i];
            const int end   = row_ptr[i + 1];
            auto body = [&](uint lo, uint hi, uint xp) {
                float x0 = __uint_as_float(xp << 16);
                float x1 = __uint_as_float(xp & 0xffff0000u);
                float v0 = __uint_as_float(lo << 16);
                float v1 = __uint_as_float(lo & 0xffff0000u);
                float v2 = __uint_as_float(hi << 16);
                float v3 = __uint_as_float(hi & 0xffff0000u);
                acc[0][0] = fmaf(v0, x0, acc[0][0]); acc[0][1] = fmaf(v0, x1, acc[0][1]);
                acc[1][0] = fmaf(v1, x0, acc[1][0]); acc[1][1] = fmaf(v1, x1, acc[1][1]);
                acc[2][0] = fmaf(v2, x0, acc[2][0]); acc[2][1] = fmaf(v2, x1, acc[2][1]);
                acc[3][0] = fmaf(v3, x0, acc[3][0]); acc[3][1] = fmaf(v3, x1, acc[3][1]);
            };
            int j = start;
            for (; j + 4 <= end; j += 4) {
                uint4 r0 = recs[j + 0];
                uint4 r1 = recs[j + 1];
                uint4 r2 = recs[j + 2];
                uint4 r3 = recs[j + 3];
                uint xp0 = *reinterpret_cast<const uint*>(xbf + ((size_t)r0.z << 7) + (l << 1));
                uint xp1 = *reinterpret_cast<const uint*>(xbf + ((size_t)r1.z << 7) + (l << 1));
                uint xp2 = *reinterpret_cast<const uint*>(xbf + ((size_t)r2.z << 7) + (l << 1));
                uint xp3 = *reinterpret_cast<const uint*>(xbf + ((size_t)r3.z << 7) + (l << 1));
                body(r0.x, r0.y, xp0);
                body(r1.x, r1.y, xp1);
                body(r2.x, r2.y, xp2);
                body(r3.x, r3.y, xp3);
            }
            for (; j < end; ++j) {
                uint4 rc = recs[j];
                uint xp = *reinterpret_cast<const uint*>(xbf + ((size_t)rc.z << 7) + (l << 1));
                body(rc.x, rc.y, xp);
            }
        }
        // write LDS: logical (lr, kdim=k*128+2l(,+1)) at byte lr*1024 + k*256 + l*4, swizzled
        const int swz = (lr & 7) << 4;
        #pragma unroll
        for (int k = 0; k < 4; ++k) {
            int byte = lr * 1024 + k * 256 + (l << 2);
            byte ^= swz;
            *reinterpret_cast<uint*>((char*)tile + byte) =
                f2bf(acc[k][0]) | (f2bf(acc[k][1]) << 16);
        }
    }
    __syncthreads();

    // ---- phase 2: wave w computes output cols [w*32, w*32+32) for the 16 rows ----
    f32x4 c2[2];
    c2[0] = (f32x4){0.f, 0.f, 0.f, 0.f};
    c2[1] = (f32x4){0.f, 0.f, 0.f, 0.f};
    const u16* wpb = W2p + ((size_t)l << 3);
    const int arow = l & 15;
    const int aswz = (arow & 7) << 4;
    #pragma unroll 4
    for (int ks = 0; ks < 16; ++ks) {
        int byte = arow * 1024 + ks * 64 + ((l >> 4) << 4);
        byte ^= aswz;
        bf16x8 a = *reinterpret_cast<const bf16x8*>((char*)tile + byte);
        #pragma unroll
        for (int nf2 = 0; nf2 < 2; ++nf2) {
            int nf = w * 2 + nf2;
            bf16x8 b = *reinterpret_cast<const bf16x8*>(wpb + (((size_t)((nf << 4) + ks)) << 9));
            c2[nf2] = __builtin_amdgcn_mfma_f32_16x16x32_bf16(a, b, c2[nf2], 0, 0, 0);
        }
    }
    const int cq = l >> 4, cr = l & 15;
    #pragma unroll
    for (int nf2 = 0; nf2 < 2; ++nf2) {
        int colf = (w * 2 + nf2) * 16 + cr;
        float bv = bias[colf];
        #pragma unroll
        for (int j = 0; j < 4; ++j) {
            int rowi = rbase + cq * 4 + j;
            if (rowi < n)
                out[(size_t)rowi * OUT_F + colf] = c2[nf2][j] + bv;
        }
    }
}

// ---------------- launch ----------------

extern "C" void kernel_launch(void* const* d_in, const int* in_sizes, int n_in,
                              void* d_out, int out_size, void* d_ws, size_t ws_size,
                              hipStream_t stream) {
    const float* x      = (const float*)d_in[0];
    const int*   edge   = (const int*)d_in[1];
    const float* weight = (const float*)d_in[2];
    const float* bias   = (const float*)d_in[3];
    const float* mu     = (const float*)d_in[4];
    const float* sig    = (const float*)d_in[5];
    float* out = (float*)d_out;

    const int n = in_sizes[0] / IN_F;
    const int E = in_sizes[1] / 2;
    const int* row = edge;
    const int* col = edge + E;
    const int nchunk = (E + CHUNK - 1) / CHUNK;

    char* ws = (char*)d_ws;
    size_t off = 0;
    auto alloc = [&](size_t bytes) {
        size_t o = off;
        off = (off + bytes + 255) & ~(size_t)255;
        return o;
    };
    u16*    xbf      = (u16*)(ws + alloc((size_t)n * IN_F * 2));
    float4* dom      = (float4*)(ws + alloc((size_t)n * 16));
    uint4*  recs     = (uint4*)(ws + alloc((size_t)E * 16));
    u16*    W2p      = (u16*)(ws + alloc((size_t)KER * IN_F * OUT_F * 2));
    u16*    hist     = (u16*)(ws + alloc((size_t)nchunk * n * 2));
    u16*    bases    = (u16*)(ws + alloc((size_t)nchunk * n * 2));
    int*    posbase  = (int*)(ws + alloc((size_t)nchunk * n * 4));
    int*    counts   = (int*)(ws + alloc((size_t)n * 4));
    int*    row_ptr  = (int*)(ws + alloc(((size_t)n + 1) * 4));
    int*    bsum     = (int*)(ws + alloc(1024 * 4));
    float*  kc       = (float*)(ws + alloc(32 * 4));
    if (off > ws_size) return;  // insufficient workspace: fail visibly rather than corrupt

    const int nB1 = (n * 32 + 255) / 256;
    const int nB2 = 32;
    prep_kernel<<<nB1 + nB2 + 1, 256, 0, stream>>>(x, weight, mu, sig, n, xbf, dom, W2p,
                                                   kc, bsum, nB1, nB2);
    const int wq = (n + 1) >> 1;
    const size_t hist_lds = (size_t)((wq + 1) >> 1) * 4;
    hist_kernel<<<nchunk * 2, 1024, hist_lds, stream>>>(row, E, n, hist);
    colscan_kernel<<<(n + 255) / 256, 256, 0, stream>>>(hist, bases, counts, bsum, n, nchunk);
    const int nb = (n + 1023) / 1024;   // 49 for n=50000; scanC requires nb <= 64
    scanC_kernel<<<nb, 1024, 0, stream>>>(counts, n, bsum, bases, posbase, row_ptr, nchunk);
    const int wp = (n + 7) >> 3;
    const size_t place_lds = (size_t)((wp + 1) >> 1) * 4;
    place_kernel<<<nchunk * 8, 1024, place_lds, stream>>>(row, col, E, n, posbase,
                                                          dom, kc, recs);
    aggemm_kernel<<<(n + 15) / 16, 256, 0, stream>>>(xbf, row_ptr, recs, W2p, bias, out, n);
}